// Round 2
// baseline (516.020 us; speedup 1.0000x reference)
//
#include <hip/hip_runtime.h>
#include <stdint.h>

#define OBS_LEN 12
#define KS 20
#define BB 2048
#define HD 128
#define MIDD 256
#define NCQ 2

using f32x4  = __attribute__((ext_vector_type(4))) float;
using bf16x8 = __attribute__((ext_vector_type(8))) short;

static __device__ __forceinline__ short f2bf(float f){
  return __builtin_bit_cast(short, (__bf16)f);   // RNE convert
}
static __device__ __forceinline__ float hsig(float x){
  return fminf(fmaxf(fmaf(x, 0.16666666666666666f, 0.5f), 0.f), 1.f);
}
static __device__ __forceinline__ float clip1(float x){
  return fminf(fmaxf(x, -1.f), 1.f);
}
static __device__ __forceinline__ f32x4 mm(bf16x8 a, bf16x8 b, f32x4 c){
  return __builtin_amdgcn_mfma_f32_16x16x32_bf16(a, b, c, 0, 0, 0);
}
static __device__ __forceinline__ bf16x8 ldh(const uint16_t* buf, int row, int q, int p){
  return *reinterpret_cast<const bf16x8*>(&buf[(row*HD + q*32 + p*8) ^ ((row&7)*8)]);
}
static __device__ __forceinline__ bf16x8 lda(const uint16_t* buf, int row, int q, int p){
  return *reinterpret_cast<const bf16x8*>(&buf[(row*MIDD + q*32 + p*8) ^ ((row&7)*8)]);
}
// stage 32x128 fp32 -> bf16 LDS tile, swizzled (^((row&7)*8) on element index)
static __device__ __forceinline__ void stage_h(const float* __restrict__ src,
                                               uint16_t* dst, int tid){
  #pragma unroll
  for (int it=0; it<4; ++it){
    int u = tid + it*256;
    int row = u >> 5, c4 = (u & 31)*4;
    float4 v = *reinterpret_cast<const float4*>(src + row*HD + c4);
    int e = (row*HD + c4) ^ ((row&7)*8);
    uint32_t lo = (uint32_t)(uint16_t)f2bf(v.x) | ((uint32_t)(uint16_t)f2bf(v.y) << 16);
    uint32_t hi = (uint32_t)(uint16_t)f2bf(v.z) | ((uint32_t)(uint16_t)f2bf(v.w) << 16);
    *reinterpret_cast<uint32_t*>(&dst[e])   = lo;
    *reinterpret_cast<uint32_t*>(&dst[e+2]) = hi;
  }
}

template<bool HASB>
static __device__ __forceinline__ void process_pair(
    int kkA, int kkB, int b0,
    const float* __restrict__ pred,
    const float* __restrict__ mw0, const float* __restrict__ mb0,
    const float* __restrict__ mw1, const float* __restrict__ mb1,
    float ob,
    const bf16x8 (&wfrag)[8][4], const bf16x8 (&wfragO)[4],
    const float (&wihA_)[8], const float (&wihB_)[8], const float (&biasv)[8],
    uint16_t (*hA)[32*HD], uint16_t (*hB)[32*HD],
    uint16_t* abufA, uint16_t* abufB,
    const float2 (&xbuf)[OBS_LEN][32],
    float* __restrict__ outp,
    int tid, int p, int ln, int wofs, bool w3)
{
  __syncthreads();   // WAR: previous pair's readers of hbuf done before restage

  // ---- stage h0 for both chunks ----
  stage_h(pred + ((size_t)(kkA*BB + b0))*HD, hA[0], tid);
  if constexpr (HASB) stage_h(pred + ((size_t)(kkB*BB + b0))*HD, hB[0], tid);
  __syncthreads();

  // ---- MLP GEMM1: [32,128] @ map_w0 -> [32,256], leaky_relu ----
  f32x4 a1A[2][4], a1B[2][4];
  #pragma unroll
  for (int ct=0; ct<4; ++ct){
    float mb = mb0[wofs*2 + ct*16 + ln];
    f32x4 v = {mb, mb, mb, mb};
    a1A[0][ct] = v; a1A[1][ct] = v;
    if constexpr (HASB) { a1B[0][ct] = v; a1B[1][ct] = v; }
  }
  #pragma unroll
  for (int q=0; q<4; ++q){
    bf16x8 aA0 = ldh(hA[0], ln, q, p), aA1 = ldh(hA[0], 16+ln, q, p);
    bf16x8 aB0, aB1;
    if constexpr (HASB) { aB0 = ldh(hB[0], ln, q, p); aB1 = ldh(hB[0], 16+ln, q, p); }
    #pragma unroll
    for (int ct=0; ct<4; ++ct){
      bf16x8 wf;
      #pragma unroll
      for (int j=0; j<8; ++j)
        wf[j] = f2bf(mw0[(q*32 + p*8 + j)*MIDD + (wofs*2 + ct*16 + ln)]);
      a1A[0][ct] = mm(aA0, wf, a1A[0][ct]);
      a1A[1][ct] = mm(aA1, wf, a1A[1][ct]);
      if constexpr (HASB) {
        a1B[0][ct] = mm(aB0, wf, a1B[0][ct]);
        a1B[1][ct] = mm(aB1, wf, a1B[1][ct]);
      }
    }
  }
  #pragma unroll
  for (int rt=0; rt<2; ++rt)
  #pragma unroll
  for (int ct=0; ct<4; ++ct)
  #pragma unroll
  for (int r=0; r<4; ++r){
    int row = rt*16 + p*4 + r;
    int e = (row*MIDD + wofs*2 + ct*16 + ln) ^ ((row&7)*8);
    float vA = a1A[rt][ct][r];
    abufA[e] = (uint16_t)f2bf(vA > 0.f ? vA : 0.01f*vA);
    if constexpr (HASB) {
      float vB = a1B[rt][ct][r];
      abufB[e] = (uint16_t)f2bf(vB > 0.f ? vB : 0.01f*vB);
    }
  }
  __syncthreads();

  // ---- MLP GEMM2: [32,256] @ map_w1 -> h_init [32,128] ----
  f32x4 a2A[2][2], a2B[2][2];
  #pragma unroll
  for (int d=0; d<2; ++d){
    float mb = mb1[wofs + d*16 + ln];
    f32x4 v = {mb, mb, mb, mb};
    a2A[0][d] = v; a2A[1][d] = v;
    if constexpr (HASB) { a2B[0][d] = v; a2B[1][d] = v; }
  }
  #pragma unroll
  for (int q=0; q<8; ++q){
    bf16x8 aA0 = lda(abufA, ln, q, p), aA1 = lda(abufA, 16+ln, q, p);
    bf16x8 aB0, aB1;
    if constexpr (HASB) { aB0 = lda(abufB, ln, q, p); aB1 = lda(abufB, 16+ln, q, p); }
    #pragma unroll
    for (int d=0; d<2; ++d){
      bf16x8 wf;
      #pragma unroll
      for (int j=0; j<8; ++j)
        wf[j] = f2bf(mw1[(q*32 + p*8 + j)*HD + (wofs + d*16 + ln)]);
      a2A[0][d] = mm(aA0, wf, a2A[0][d]);
      a2A[1][d] = mm(aA1, wf, a2A[1][d]);
      if constexpr (HASB) {
        a2B[0][d] = mm(aB0, wf, a2B[0][d]);
        a2B[1][d] = mm(aB1, wf, a2B[1][d]);
      }
    }
  }
  float cA[2][2][4], cB[2][2][4];
  #pragma unroll
  for (int rt=0; rt<2; ++rt)
  #pragma unroll
  for (int d=0; d<2; ++d)
  #pragma unroll
  for (int r=0; r<4; ++r){
    int row = rt*16 + p*4 + r;
    int e = (row*HD + wofs + d*16 + ln) ^ ((row&7)*8);
    hA[0][e] = (uint16_t)f2bf(a2A[rt][d][r]);
    cA[rt][d][r] = 0.f;
    if constexpr (HASB) {
      hB[0][e] = (uint16_t)f2bf(a2B[rt][d][r]);
      cB[rt][d][r] = 0.f;
    }
  }
  __syncthreads();

  // ---- 12 recurrent steps, two chunks interleaved ----
  f32x4 accA[2][8], accB[2][8];
  f32x4 a8A[2], a8B[2];
  for (int t=0; t<OBS_LEN; ++t){
    const int cur = t & 1, nxt = cur ^ 1;
    // C-init = x@w_ih^T + bias (identical for A and B: x doesn't depend on k)
    #pragma unroll
    for (int rt=0; rt<2; ++rt){
      float2 xv[4];
      #pragma unroll
      for (int r=0; r<4; ++r) xv[r] = xbuf[t][rt*16 + p*4 + r];
      #pragma unroll
      for (int ct=0; ct<8; ++ct){
        f32x4 a;
        #pragma unroll
        for (int r=0; r<4; ++r)
          a[r] = fmaf(xv[r].x, wihA_[ct], fmaf(xv[r].y, wihB_[ct], biasv[ct]));
        accA[rt][ct] = a;
        if constexpr (HASB) accB[rt][ct] = a;
      }
    }
    if (w3){
      f32x4 v = {ob,ob,ob,ob};
      a8A[0] = v; a8A[1] = v;
      if constexpr (HASB) { a8B[0] = v; a8B[1] = v; }
    }
    #pragma unroll
    for (int q=0; q<4; ++q){
      bf16x8 aA0 = ldh(hA[cur], ln, q, p), aA1 = ldh(hA[cur], 16+ln, q, p);
      bf16x8 aB0, aB1;
      if constexpr (HASB) { aB0 = ldh(hB[cur], ln, q, p); aB1 = ldh(hB[cur], 16+ln, q, p); }
      #pragma unroll
      for (int ct=0; ct<8; ++ct){
        accA[0][ct] = mm(aA0, wfrag[ct][q], accA[0][ct]);
        accA[1][ct] = mm(aA1, wfrag[ct][q], accA[1][ct]);
        if constexpr (HASB) {
          accB[0][ct] = mm(aB0, wfrag[ct][q], accB[0][ct]);
          accB[1][ct] = mm(aB1, wfrag[ct][q], accB[1][ct]);
        }
      }
      if (w3){
        a8A[0] = mm(aA0, wfragO[q], a8A[0]);
        a8A[1] = mm(aA1, wfragO[q], a8A[1]);
        if constexpr (HASB) {
          a8B[0] = mm(aB0, wfragO[q], a8B[0]);
          a8B[1] = mm(aB1, wfragO[q], a8B[1]);
        }
      }
    }
    if (w3 && t > 0 && ln < NCQ){
      #pragma unroll
      for (int rt=0; rt<2; ++rt)
      #pragma unroll
      for (int r=0; r<4; ++r){
        int cell = rt*16 + p*4 + r;
        outp[(((size_t)(t-1)*KS + kkA)*BB + b0 + cell)*NCQ + ln] = a8A[rt][r];
        if constexpr (HASB)
          outp[(((size_t)(t-1)*KS + kkB)*BB + b0 + cell)*NCQ + ln] = a8B[rt][r];
      }
    }
    // gate math fp32; h_new -> bf16 -> h[nxt]
    #pragma unroll
    for (int rt=0; rt<2; ++rt)
    #pragma unroll
    for (int d=0; d<2; ++d)
    #pragma unroll
    for (int r=0; r<4; ++r){
      int row = rt*16 + p*4 + r;
      int e = (row*HD + wofs + d*16 + ln) ^ ((row&7)*8);
      {
        float iv = hsig(accA[rt][0+d][r]);
        float fv = hsig(accA[rt][2+d][r]);
        float gv = clip1(accA[rt][4+d][r]);
        float ov = hsig(accA[rt][6+d][r]);
        float cv = fmaf(fv, cA[rt][d][r], iv*gv);
        cA[rt][d][r] = cv;
        hA[nxt][e] = (uint16_t)f2bf(ov * clip1(cv));
      }
      if constexpr (HASB) {
        float iv = hsig(accB[rt][0+d][r]);
        float fv = hsig(accB[rt][2+d][r]);
        float gv = clip1(accB[rt][4+d][r]);
        float ov = hsig(accB[rt][6+d][r]);
        float cv = fmaf(fv, cB[rt][d][r], iv*gv);
        cB[rt][d][r] = cv;
        hB[nxt][e] = (uint16_t)f2bf(ov * clip1(cv));
      }
    }
    __syncthreads();
  }

  // ---- final out_11 = h_11 @ out_w + out_b (h_11 is in dbuf 0) ----
  if (w3){
    f32x4 oA0 = {ob,ob,ob,ob}, oA1 = oA0, oB0 = oA0, oB1 = oA0;
    #pragma unroll
    for (int q=0; q<4; ++q){
      bf16x8 aA0 = ldh(hA[0], ln, q, p), aA1 = ldh(hA[0], 16+ln, q, p);
      oA0 = mm(aA0, wfragO[q], oA0);
      oA1 = mm(aA1, wfragO[q], oA1);
      if constexpr (HASB) {
        bf16x8 aB0 = ldh(hB[0], ln, q, p), aB1 = ldh(hB[0], 16+ln, q, p);
        oB0 = mm(aB0, wfragO[q], oB0);
        oB1 = mm(aB1, wfragO[q], oB1);
      }
    }
    if (ln < NCQ){
      #pragma unroll
      for (int r=0; r<4; ++r){
        outp[(((size_t)11*KS + kkA)*BB + b0 +      (p*4 + r))*NCQ + ln] = oA0[r];
        outp[(((size_t)11*KS + kkA)*BB + b0 + 16 + (p*4 + r))*NCQ + ln] = oA1[r];
        if constexpr (HASB) {
          outp[(((size_t)11*KS + kkB)*BB + b0 +      (p*4 + r))*NCQ + ln] = oB0[r];
          outp[(((size_t)11*KS + kkB)*BB + b0 + 16 + (p*4 + r))*NCQ + ln] = oB1[r];
        }
      }
    }
  }
}

__global__ __launch_bounds__(256, 1)
void CRMF_35296041239144_kernel(
    const float* __restrict__ obs,  const float* __restrict__ pred,
    const float* __restrict__ mw0,  const float* __restrict__ mb0,
    const float* __restrict__ mw1,  const float* __restrict__ mb1,
    const float* __restrict__ wih,  const float* __restrict__ whh,
    const float* __restrict__ bih,  const float* __restrict__ bhh,
    const float* __restrict__ oww,  const float* __restrict__ obb,
    float* __restrict__ outp)
{
  __shared__ __align__(16) uint16_t hbufA[2][32*HD];
  __shared__ __align__(16) uint16_t hbufB[2][32*HD];
  __shared__ __align__(16) uint16_t abufA[32*MIDD];
  __shared__ __align__(16) uint16_t abufB[32*MIDD];
  __shared__ float2 xbuf[OBS_LEN][32];

  const int tid = threadIdx.x;
  const int w   = tid >> 6;
  const int l   = tid & 63;
  const int p   = l >> 4;
  const int ln  = l & 15;
  const int wofs = w * 32;
  const bool w3 = (w == 3);

  const int b  = blockIdx.x;        // 256 blocks, 1 per CU
  const int q0 = b >> 6;            // k base (k = q0 + 4j)
  const int b0 = (b & 63) * 32;     // batch base (same for all 5 chunks)

  // ---- stage shifted obs once per block ----
  for (int u = tid; u < OBS_LEN*32; u += 256){
    int t = u >> 5, cc = u & 31;
    int st = t ? (t-1) : 0;
    const float* pp = obs + ((size_t)st*BB + b0 + cc)*3;
    xbuf[t][cc] = make_float2(pp[0], pp[1]);
  }

  // ---- recurrent weights -> registers ONCE per block ----
  bf16x8 wfrag[8][4];
  float wihA_[8], wihB_[8], biasv[8];
  #pragma unroll
  for (int ct=0; ct<8; ++ct){
    int col = (ct>>1)*128 + wofs + (ct&1)*16 + ln;   // gate*128 + hdim
    wihA_[ct] = wih[col*2];
    wihB_[ct] = wih[col*2+1];
    biasv[ct] = bih[col] + bhh[col];
    #pragma unroll
    for (int q=0; q<4; ++q){
      const float* s = whh + col*HD + q*32 + p*8;
      float4 f0 = *reinterpret_cast<const float4*>(s);
      float4 f1 = *reinterpret_cast<const float4*>(s+4);
      bf16x8 wf;
      wf[0]=f2bf(f0.x); wf[1]=f2bf(f0.y); wf[2]=f2bf(f0.z); wf[3]=f2bf(f0.w);
      wf[4]=f2bf(f1.x); wf[5]=f2bf(f1.y); wf[6]=f2bf(f1.z); wf[7]=f2bf(f1.w);
      wfrag[ct][q] = wf;
    }
  }
  bf16x8 wfragO[4];
  float ob = 0.f;
  if (w3){
    #pragma unroll
    for (int q=0; q<4; ++q){
      bf16x8 wf;
      #pragma unroll
      for (int j=0; j<8; ++j){
        int k = q*32 + p*8 + j;
        wf[j] = (ln < NCQ) ? f2bf(oww[k*NCQ + ln]) : (short)0;
      }
      wfragO[q] = wf;
    }
    if (ln < NCQ) ob = obb[ln];
  }

  // ---- 5 chunks: 2 interleaved pairs + 1 solo tail ----
  process_pair<true >(q0,      q0 + 4,  b0, pred, mw0, mb0, mw1, mb1, ob,
                      wfrag, wfragO, wihA_, wihB_, biasv,
                      hbufA, hbufB, abufA, abufB, xbuf, outp, tid, p, ln, wofs, w3);
  process_pair<true >(q0 + 8,  q0 + 12, b0, pred, mw0, mb0, mw1, mb1, ob,
                      wfrag, wfragO, wihA_, wihB_, biasv,
                      hbufA, hbufB, abufA, abufB, xbuf, outp, tid, p, ln, wofs, w3);
  process_pair<false>(q0 + 16, q0 + 16, b0, pred, mw0, mb0, mw1, mb1, ob,
                      wfrag, wfragO, wihA_, wihB_, biasv,
                      hbufA, hbufB, abufA, abufB, xbuf, outp, tid, p, ln, wofs, w3);
}

extern "C" void kernel_launch(void* const* d_in, const int* in_sizes, int n_in,
                              void* d_out, int out_size, void* d_ws, size_t ws_size,
                              hipStream_t stream) {
  (void)in_sizes; (void)n_in; (void)d_ws; (void)ws_size; (void)out_size;
  CRMF_35296041239144_kernel<<<dim3(256), dim3(256), 0, stream>>>(
      (const float*)d_in[0], (const float*)d_in[1], (const float*)d_in[2],
      (const float*)d_in[3], (const float*)d_in[4], (const float*)d_in[5],
      (const float*)d_in[6], (const float*)d_in[7], (const float*)d_in[8],
      (const float*)d_in[9], (const float*)d_in[10], (const float*)d_in[11],
      (float*)d_out);
}